// Round 18
// baseline (773.141 us; speedup 1.0000x reference)
//
#include <hip/hip_runtime.h>
#include <hip/hip_bf16.h>
#include <math.h>

#define SHIFT_ 4

typedef __attribute__((ext_vector_type(8))) short bh8;
typedef __attribute__((ext_vector_type(4))) short sh4;
typedef __attribute__((ext_vector_type(4))) float f4;
typedef __attribute__((ext_vector_type(8))) __bf16 bf8t;

static __device__ __forceinline__ f4 mfma16(bh8 a, bh8 b, f4 c){
  return __builtin_amdgcn_mfma_f32_16x16x32_bf16(
    __builtin_bit_cast(bf8t, a), __builtin_bit_cast(bf8t, b), c, 0, 0, 0);
}
static __device__ __forceinline__ unsigned short f2b(float f){
  unsigned u = __builtin_bit_cast(unsigned, f);
  u += 0x7fffu + ((u >> 16) & 1u);
  return (unsigned short)(u >> 16);
}
static __device__ __forceinline__ float b2f(unsigned short h){
  return __builtin_bit_cast(float, ((unsigned)h) << 16);
}
static __device__ __forceinline__ unsigned cvt_pk_bf16(float lo, float hi){
  unsigned r;
  asm("v_cvt_pk_bf16_f32 %0, %1, %2" : "=v"(r) : "v"(lo), "v"(hi));
  return r;
}
static __device__ __forceinline__ float gelu_f(float hv){
  float u = hv * (1.5957691216f + 0.0713548162f * hv * hv);
  return hv * __builtin_amdgcn_rcpf(1.f + __expf(-u));
}
static __device__ __forceinline__ void glds16(const unsigned short* g, unsigned short* l){
  __builtin_amdgcn_global_load_lds(
    (const __attribute__((address_space(1))) unsigned int*)g,
    (__attribute__((address_space(3))) unsigned int*)l, 16, 0, 0);
}

// ---------------- kernel 0: weights f32 -> bf16 (qw pre-scaled by d^-0.5) ---
__global__ __launch_bounds__(256) void prep_w(
    const float* __restrict__ qw, const float* __restrict__ kvw,
    const float* __restrict__ pw, const float* __restrict__ w1,
    const float* __restrict__ w2, unsigned short* __restrict__ wb){
  int i = blockIdx.x * 256 + threadIdx.x;   // 786432 total
  float v;
  if      (i < 65536)  v = qw[i] * 0.17677669529663687f;
  else if (i < 196608) v = kvw[i - 65536];
  else if (i < 262144) v = pw[i - 196608];
  else if (i < 524288) v = w1[i - 262144];
  else                 v = w2[i - 524288];
  wb[i] = f2b(v);
}

// ---------------- kernel 1: LN1 + roll(-4,-4) + window partition ------------
__global__ __launch_bounds__(256) void ln1_win(
    const float* __restrict__ x, const float* __restrict__ g1,
    const float* __restrict__ b1,
    unsigned short* __restrict__ q_in, unsigned short* __restrict__ kv_in){
  int rid  = blockIdx.x * 4 + (threadIdx.x >> 6);   // 0..262143
  int lane = threadIdx.x & 63;
  int d    = rid >> 17;
  int rem  = rid & 131071;          // w*64 + n
  int w = rem >> 6, n = rem & 63;
  int b = w >> 10, hb = (w >> 5) & 31, wbk = w & 31;
  int sh = (hb * 8 + (n >> 3) + SHIFT_) & 255;
  int sw = (wbk * 8 + (n & 7) + SHIFT_) & 255;
  const float* src = x + ((((size_t)(b * 2 + d)) * 256 + sh) * 256 + sw) * 256;
  float4 v = *(const float4*)(src + lane * 4);
  float s  = v.x + v.y + v.z + v.w;
  float ss = v.x * v.x + v.y * v.y + v.z * v.z + v.w * v.w;
  #pragma unroll
  for (int off = 1; off < 64; off <<= 1){ s += __shfl_xor(s, off); ss += __shfl_xor(ss, off); }
  float m    = s * (1.f / 256.f);
  float rstd = rsqrtf(ss * (1.f / 256.f) - m * m + 1e-5f);
  int c = lane * 4;
  float4 g  = *(const float4*)(g1 + c);
  float4 bb = *(const float4*)(b1 + c);
  sh4 o;
  o.x = (short)f2b((v.x - m) * rstd * g.x + bb.x);
  o.y = (short)f2b((v.y - m) * rstd * g.y + bb.y);
  o.z = (short)f2b((v.z - m) * rstd * g.z + bb.z);
  o.w = (short)f2b((v.w - m) * rstd * g.w + bb.w);
  unsigned short* dst = (d == 0 ? q_in : kv_in) + (size_t)rem * 256 + c;
  *(sh4*)dst = o;
}

// ---------------- fused QKV GEMM: 512 thr, block 128 rows x 3x256 cols ------
// kv A-panel (all 4 K-tiles) prefetched into REGISTERS at kernel start; its
// HBM latency hides under the whole q GEMM. nt=1/2 stage A via ds_write from
// regs (no global load, no HBM drain at barriers; kv_in read ONCE).
__global__ __launch_bounds__(512, 4) void qkv_gemm(
    const unsigned short* __restrict__ q_in, const unsigned short* __restrict__ kv_in,
    const unsigned short* __restrict__ wpack,
    const float* __restrict__ qbias, const float* __restrict__ kvbias,
    unsigned short* __restrict__ qo, unsigned short* __restrict__ ko,
    unsigned short* __restrict__ vo){
  __shared__ unsigned short sMem[24576];   // 48KB: sA 128x64 | sB 256x64 ; sO aliases
  unsigned short (*sA)[64]  = (unsigned short(*)[64])sMem;
  unsigned short (*sB)[64]  = (unsigned short(*)[64])(sMem + 8192);
  unsigned short (*sO)[136] = (unsigned short(*)[136])sMem;   // 128x136 = 34.8KB
  int m0 = blockIdx.x * 128;
  int tid = threadIdx.x, lane = tid & 63, wid = tid >> 6;   // 8 waves
  int wm = wid >> 2, wn = wid & 3;
  int llo = lane & 15, lhi = lane >> 4;
  int lr = lane >> 3, lc = (lane & 7) * 8;
  // prefetch kv A-panel (4 K-tiles) into registers; latency hides under nt=0
  bh8 kvreg[4][2];
  #pragma unroll
  for (int t = 0; t < 4; t++)
    #pragma unroll
    for (int c = 0; c < 2; c++){
      int rr = wid * 16 + c * 8;
      kvreg[t][c] = *(const bh8*)(kv_in + (size_t)(m0 + rr + lr) * 256 + t * 64 + lc);
    }
  const f4 FZ = {0.f, 0.f, 0.f, 0.f};
  for (int nt = 0; nt < 3; nt++){
    const unsigned short* Wt = wpack + nt * 65536;
    const float* bias = (nt == 0) ? qbias : kvbias + (nt - 1) * 256;
    unsigned short* outb = (nt == 0) ? qo : (nt == 1 ? ko : vo);
    float bscale = (nt == 0) ? 0.17677669529663687f : 1.f;
    f4 acc[4][4];
    for (int i = 0; i < 4; i++) for (int j = 0; j < 4; j++) acc[i][j] = FZ;
    #pragma unroll
    for (int t = 0; t < 4; t++){
      int k0 = t * 64;
      if (nt == 0){
        #pragma unroll
        for (int c = 0; c < 2; c++){
          int rr = wid * 16 + c * 8;
          glds16(q_in + (size_t)(m0 + rr + lr) * 256 + k0 + lc, &sA[rr][0]);
        }
      } else {
        // stage A from registers: pure LDS writes, no global traffic
        #pragma unroll
        for (int c = 0; c < 2; c++){
          int rr = wid * 16 + c * 8;
          *(bh8*)&sA[rr + lr][lc] = kvreg[t][c];
        }
      }
      #pragma unroll
      for (int c = 0; c < 4; c++){
        int rb = wid * 32 + c * 8;
        glds16(Wt + (size_t)(rb + lr) * 256 + k0 + lc, &sB[rb][0]);
      }
      __syncthreads();
      #pragma unroll
      for (int ks = 0; ks < 2; ks++){
        bh8 a[4], b[4];
        #pragma unroll
        for (int mi = 0; mi < 4; mi++) a[mi] = *(const bh8*)&sA[wm * 64 + mi * 16 + llo][ks * 32 + lhi * 8];
        #pragma unroll
        for (int nj = 0; nj < 4; nj++) b[nj] = *(const bh8*)&sB[wn * 64 + nj * 16 + llo][ks * 32 + lhi * 8];
        #pragma unroll
        for (int mi = 0; mi < 4; mi++)
          #pragma unroll
          for (int nj = 0; nj < 4; nj++)
            acc[mi][nj] = mfma16(b[nj], a[mi], acc[mi][nj]);   // swapped
      }
      __syncthreads();
    }
    // LDS-staged epilogue, two 128-col halves
    #pragma unroll
    for (int half = 0; half < 2; half++){
      if ((wn >> 1) == half){
        int cbase = (wn & 1) * 64;
        #pragma unroll
        for (int nj = 0; nj < 4; nj++){
          int cb = cbase + nj * 16 + lhi * 4;
          float4 bv = *(const float4*)(bias + half * 128 + cb);
          #pragma unroll
          for (int mi = 0; mi < 4; mi++){
            int rl = wm * 64 + mi * 16 + llo;
            uint2 p;
            p.x = cvt_pk_bf16(acc[mi][nj][0] + bv.x * bscale, acc[mi][nj][1] + bv.y * bscale);
            p.y = cvt_pk_bf16(acc[mi][nj][2] + bv.z * bscale, acc[mi][nj][3] + bv.w * bscale);
            *(uint2*)&sO[rl][cb] = p;
          }
        }
      }
      __syncthreads();
      #pragma unroll
      for (int it = 0; it < 4; it++){
        int idx = tid + it * 512;            // 0..2047 = 128 rows x 16 chunks
        int rl = idx >> 4, ch = (idx & 15) * 8;
        bh8 vv = *(const bh8*)&sO[rl][ch];
        *(bh8*)(outb + (size_t)(m0 + rl) * 256 + half * 128 + ch) = vv;
      }
      __syncthreads();   // sO reads done before next write/restage
    }
  }
}

// ---------------- kernel 3: attention, block = (window, 4-head group) -------
__global__ __launch_bounds__(256, 4) void attn_k(
    const unsigned short* __restrict__ q, const unsigned short* __restrict__ k,
    const unsigned short* __restrict__ v, const float* __restrict__ mask,
    const float* __restrict__ bias_table, unsigned short* __restrict__ aout){
  __shared__ unsigned short sMask[64][72];   // bf16 mask
  __shared__ unsigned short sVT[128][72];    // V^T (d-local x n) for this group
  __shared__ unsigned short sP[4][64][72];
  __shared__ float sBias[4][225];
  int bid = blockIdx.x;                      // 4096 = 2048 windows x 2 groups
  int w = bid >> 1, hg = bid & 1;
  int tid = threadIdx.x, lane = tid & 63, wid = tid >> 6;
  int hd = hg * 4 + wid;
  int llo = lane & 15, lhi = lane >> 4;
  const unsigned short* qp = q + (size_t)w * 64 * 256 + hd * 32;
  const unsigned short* kp = k + (size_t)w * 64 * 256 + hd * 32;
  bh8 af[4], bf[4];
  #pragma unroll
  for (int mi = 0; mi < 4; mi++) af[mi] = *(const bh8*)(qp + (size_t)(mi * 16 + llo) * 256 + lhi * 8);
  #pragma unroll
  for (int nj = 0; nj < 4; nj++) bf[nj] = *(const bh8*)(kp + (size_t)(nj * 16 + llo) * 256 + lhi * 8);
  const float* mrow = mask + (size_t)(w & 1023) * 4096;
  #pragma unroll
  for (int i = 0; i < 2; i++){
    int base = (tid + i * 256) * 8;          // 0..4088
    float4 u0 = *(const float4*)(mrow + base);
    float4 u1 = *(const float4*)(mrow + base + 4);
    int rr = base >> 6, cc = base & 63;
    uint4 p;
    p.x = cvt_pk_bf16(u0.x, u0.y); p.y = cvt_pk_bf16(u0.z, u0.w);
    p.z = cvt_pk_bf16(u1.x, u1.y); p.w = cvt_pk_bf16(u1.z, u1.w);
    *(uint4*)&sMask[rr][cc] = p;
  }
  {
    const unsigned short* vp = v + (size_t)w * 64 * 256 + hg * 128;
    #pragma unroll
    for (int it = 0; it < 4; it++){
      int idx = tid + it * 256;              // 0..1023
      int n = idx >> 4, dc = (idx & 15) * 8;
      bh8 vv = *(const bh8*)(vp + (size_t)n * 256 + dc);
      #pragma unroll
      for (int j = 0; j < 8; j++) sVT[dc + j][n] = (unsigned short)vv[j];
    }
  }
  for (int i = lane; i < 225; i += 64) sBias[wid][i] = bias_table[i * 8 + hd];
  const f4 FZ = {0.f, 0.f, 0.f, 0.f};
  f4 acc[4][4];
  #pragma unroll
  for (int mi = 0; mi < 4; mi++)
    #pragma unroll
    for (int nj = 0; nj < 4; nj++)
      acc[mi][nj] = mfma16(af[mi], bf[nj], FZ);
  __syncthreads();   // sMask + sVT ready
  #pragma unroll
  for (int mi = 0; mi < 4; mi++){
    #pragma unroll
    for (int r = 0; r < 4; r++){
      int rr = mi * 16 + lhi * 4 + r;
      int yi = rr >> 3, xi = rr & 7;
      float sv[4]; float mx = -1e30f;
      #pragma unroll
      for (int nj = 0; nj < 4; nj++){
        int cc = nj * 16 + llo;
        int idx = (yi - (cc >> 3) + 7) * 15 + (xi - (cc & 7) + 7);
        sv[nj] = acc[mi][nj][r] + sBias[wid][idx] + b2f(sMask[rr][cc]);
        mx = fmaxf(mx, sv[nj]);
      }
      #pragma unroll
      for (int off = 1; off < 16; off <<= 1) mx = fmaxf(mx, __shfl_xor(mx, off));
      float sum = 0.f;
      #pragma unroll
      for (int nj = 0; nj < 4; nj++){ sv[nj] = __expf(sv[nj] - mx); sum += sv[nj]; }
      #pragma unroll
      for (int off = 1; off < 16; off <<= 1) sum += __shfl_xor(sum, off);
      float inv = __builtin_amdgcn_rcpf(sum);
      #pragma unroll
      for (int nj = 0; nj < 4; nj++) sP[wid][rr][nj * 16 + llo] = f2b(sv[nj] * inv);
    }
  }
  f4 o[4][2];
  for (int mi = 0; mi < 4; mi++) for (int dj = 0; dj < 2; dj++) o[mi][dj] = FZ;
  #pragma unroll
  for (int ks = 0; ks < 2; ks++){
    bh8 pa[4], vb[2];
    #pragma unroll
    for (int mi = 0; mi < 4; mi++) pa[mi] = *(const bh8*)&sP[wid][mi * 16 + llo][ks * 32 + lhi * 8];
    #pragma unroll
    for (int dj = 0; dj < 2; dj++) vb[dj] = *(const bh8*)&sVT[wid * 32 + dj * 16 + llo][ks * 32 + lhi * 8];
    #pragma unroll
    for (int mi = 0; mi < 4; mi++)
      #pragma unroll
      for (int dj = 0; dj < 2; dj++)
        o[mi][dj] = mfma16(pa[mi], vb[dj], o[mi][dj]);
  }
  #pragma unroll
  for (int mi = 0; mi < 4; mi++)
    for (int dj = 0; dj < 2; dj++)
      for (int r = 0; r < 4; r++){
        int rr = mi * 16 + lhi * 4 + r, dd = dj * 16 + llo;
        aout[((size_t)w * 64 + rr) * 256 + hd * 32 + dd] = f2b(o[mi][dj][r]);
      }
}

// ---------------- P-projection GEMM, swapped orientation, vector epilogue ---
__global__ __launch_bounds__(512, 4) void pgemm(
    const unsigned short* __restrict__ A, const unsigned short* __restrict__ Wt,
    const float* __restrict__ bias,
    float* __restrict__ outf, const unsigned short* __restrict__ qin,
    const float* __restrict__ xsrc){
  __shared__ unsigned short sA[128][64];
  __shared__ unsigned short sB[256][64];
  int m0 = blockIdx.x * 128;
  int tid = threadIdx.x, lane = tid & 63, wid = tid >> 6;   // 8 waves
  int wm = wid >> 2, wn = wid & 3;
  int llo = lane & 15, lhi = lane >> 4;
  int lr = lane >> 3, lc = (lane & 7) * 8;
  const f4 FZ = {0.f, 0.f, 0.f, 0.f};
  f4 acc[4][4];
  for (int i = 0; i < 4; i++) for (int j = 0; j < 4; j++) acc[i][j] = FZ;
  for (int t = 0; t < 4; t++){
    int k0 = t * 64;
    #pragma unroll
    for (int c = 0; c < 2; c++){
      int rr = wid * 16 + c * 8;
      glds16(A + (size_t)(m0 + rr + lr) * 256 + k0 + lc, &sA[rr][0]);
    }
    #pragma unroll
    for (int c = 0; c < 4; c++){
      int rb = wid * 32 + c * 8;
      glds16(Wt + (size_t)(rb + lr) * 256 + k0 + lc, &sB[rb][0]);
    }
    __syncthreads();
    #pragma unroll
    for (int ks = 0; ks < 2; ks++){
      bh8 a[4], b[4];
      #pragma unroll
      for (int mi = 0; mi < 4; mi++) a[mi] = *(const bh8*)&sA[wm * 64 + mi * 16 + llo][ks * 32 + lhi * 8];
      #pragma unroll
      for (int nj = 0; nj < 4; nj++) b[nj] = *(const bh8*)&sB[wn * 64 + nj * 16 + llo][ks * 32 + lhi * 8];
      #pragma unroll
      for (int mi = 0; mi < 4; mi++)
        #pragma unroll
        for (int nj = 0; nj < 4; nj++)
          acc[mi][nj] = mfma16(b[nj], a[mi], acc[mi][nj]);   // swapped
    }
    __syncthreads();
  }
  #pragma unroll
  for (int mi = 0; mi < 4; mi++){
    int row = m0 + wm * 64 + mi * 16 + llo;
    int w = row >> 6, n = row & 63;
    int b = w >> 10, hb = (w >> 5) & 31, wbk = w & 31;
    int hh = (hb * 8 + (n >> 3) + SHIFT_) & 255;
    int ww = (wbk * 8 + (n & 7) + SHIFT_) & 255;
    size_t rbase = (((size_t)b * 256 + hh) * 256 + ww) * 256;
    size_t xbase = (((size_t)(b * 2) * 256 + hh) * 256 + ww) * 256;
    const unsigned short* qrow = qin + (size_t)row * 256;
    #pragma unroll
    for (int nj = 0; nj < 4; nj++){
      int cb = wn * 64 + nj * 16 + lhi * 4;
      float4 bv = *(const float4*)(bias + cb);
      uint2 qv = *(const uint2*)(qrow + cb);
      float4 xv = *(const float4*)(xsrc + xbase + cb);
      float4 o;
      o.x = acc[mi][nj][0] + bv.x + b2f((unsigned short)(qv.x & 0xffff)) + xv.x;
      o.y = acc[mi][nj][1] + bv.y + b2f((unsigned short)(qv.x >> 16))    + xv.y;
      o.z = acc[mi][nj][2] + bv.z + b2f((unsigned short)(qv.y & 0xffff)) + xv.z;
      o.w = acc[mi][nj][3] + bv.w + b2f((unsigned short)(qv.y >> 16))    + xv.w;
      *(float4*)(outf + rbase + cb) = o;
    }
  }
}

// ---------------- kernel 4: LN2 -> bf16 xn (row-major) ----------------------
__global__ __launch_bounds__(256) void ln2_k(
    const float* __restrict__ x1, const float* __restrict__ g2,
    const float* __restrict__ b2, unsigned short* __restrict__ xn){
  int rid  = blockIdx.x * 4 + (threadIdx.x >> 6);   // 0..131071
  int lane = threadIdx.x & 63;
  const float* xr = x1 + (size_t)rid * 256;
  float4 v = *(const float4*)(xr + lane * 4);
  float s  = v.x + v.y + v.z + v.w;
  float ss = v.x * v.x + v.y * v.y + v.z * v.z + v.w * v.w;
  #pragma unroll
  for (int off = 1; off < 64; off <<= 1){ s += __shfl_xor(s, off); ss += __shfl_xor(ss, off); }
  float m    = s * (1.f / 256.f);
  float rstd = rsqrtf(ss * (1.f / 256.f) - m * m + 1e-5f);
  int c = lane * 4;
  float4 g  = *(const float4*)(g2 + c);
  float4 bb = *(const float4*)(b2 + c);
  sh4 o;
  o.x = (short)f2b((v.x - m) * rstd * g.x + bb.x);
  o.y = (short)f2b((v.y - m) * rstd * g.y + bb.y);
  o.z = (short)f2b((v.z - m) * rstd * g.z + bb.z);
  o.w = (short)f2b((v.w - m) * rstd * g.w + bb.w);
  *(sh4*)(xn + (size_t)rid * 256 + c) = o;
}

// ---------------- kernel 5: m97-template GEMM for the MLP -------------------
template<int KSTEPS, int EPI, int BIASF>
__global__ __launch_bounds__(256, 3) void mlp_gemm(
    const unsigned short* __restrict__ A, int lda,
    const unsigned short* __restrict__ Bw, int ldb,
    const float* __restrict__ bias,
    unsigned short* __restrict__ outb, int ldo,
    float* __restrict__ outf){
  __shared__ unsigned short sMem[17408];   // 34.8KB: sA|sB (32KB); sO aliases
  unsigned short (*sA)[64]  = (unsigned short(*)[64])sMem;
  unsigned short (*sB)[64]  = (unsigned short(*)[64])(sMem + 8192);
  unsigned short (*sO)[136] = (unsigned short(*)[136])sMem;   // 128x136
  int n0 = blockIdx.x * 128, m0 = blockIdx.y * 128;
  int tid = threadIdx.x, lane = tid & 63, wid = tid >> 6;
  int wm = wid >> 1, wn = wid & 1;
  int llo = lane & 15, lhi = lane >> 4;
  int lr = lane >> 3, lc = (lane & 7) * 8;
  const f4 FZ = {0.f, 0.f, 0.f, 0.f};
  f4 acc[4][4];
  for (int i = 0; i < 4; i++) for (int j = 0; j < 4; j++) acc[i][j] = FZ;

  for (int t = 0; t < KSTEPS; t++){
    int k0 = t * 64;
    #pragma unroll
    for (int c = 0; c < 4; c++){
      int rr = wid * 32 + c * 8 + lr;
      glds16(A  + (size_t)(m0 + rr) * lda + k0 + lc, &sA[wid * 32 + c * 8][0]);
      glds16(Bw + (size_t)(n0 + rr) * ldb + k0 + lc, &sB[wid * 32 + c * 8][0]);
    }
    __syncthreads();
    #pragma unroll
    for (int ks = 0; ks < 2; ks++){
      bh8 a[4], b[4];
      #pragma unroll
      for (int mi = 0; mi < 4; mi++) a[mi] = *(const bh8*)&sA[wm * 64 + mi * 16 + llo][ks * 32 + lhi * 8];
      #pragma unroll
      for (int nj = 0; nj < 4; nj++) b[nj] = *(const bh8*)&sB[wn * 64 + nj * 16 + llo][ks * 32 + lhi * 8];
      #pragma unroll
      for (int mi = 0; mi < 4; mi++)
        #pragma unroll
        for (int nj = 0; nj < 4; nj++){
          if (EPI == 0) acc[mi][nj] = mfma16(b[nj], a[mi], acc[mi][nj]);   // swapped
          else          acc[mi][nj] = mfma16(a[mi], b[nj], acc[mi][nj]);
        }
    }
    __syncthreads();
  }
  if (EPI == 0){
    #pragma unroll
    for (int nj = 0; nj < 4; nj++){
      int cb = wn * 64 + nj * 16 + lhi * 4;    // 0..127
      float4 bv = *(const float4*)(bias + n0 + cb);
      #pragma unroll
      for (int mi = 0; mi < 4; mi++){
        int rl = wm * 64 + mi * 16 + llo;
        uint2 p;
        p.x = cvt_pk_bf16(gelu_f(acc[mi][nj][0] + bv.x), gelu_f(acc[mi][nj][1] + bv.y));
        p.y = cvt_pk_bf16(gelu_f(acc[mi][nj][2] + bv.z), gelu_f(acc[mi][nj][3] + bv.w));
        *(uint2*)&sO[rl][cb] = p;
      }
    }
    __syncthreads();
    #pragma unroll
    for (int it = 0; it < 8; it++){
      int idx = tid + it * 256;                // 0..2047 = 128 rows x 16 chunks
      int rl = idx >> 4, ch = (idx & 15) * 8;
      bh8 vv = *(const bh8*)&sO[rl][ch];
      *(bh8*)(outb + (size_t)(m0 + rl) * ldo + n0 + ch) = vv;
    }
  } else {
    #pragma unroll
    for (int mi = 0; mi < 4; mi++)
      #pragma unroll
      for (int nj = 0; nj < 4; nj++){
        int col = n0 + wn * 64 + nj * 16 + llo;
        float bv = BIASF ? bias[col] : 0.f;
        #pragma unroll
        for (int r = 0; r < 4; r++){
          int row = m0 + wm * 64 + mi * 16 + lhi * 4 + r;
          outf[(size_t)row * 256 + col] += acc[mi][nj][r] + bv;
        }
      }
  }
}

extern "C" void kernel_launch(void* const* d_in, const int* in_sizes, int n_in,
                              void* d_out, int out_size, void* d_ws, size_t ws_size,
                              hipStream_t stream){
  const float* x          = (const float*)d_in[0];
  const float* mask       = (const float*)d_in[1];
  const float* g1         = (const float*)d_in[2];
  const float* b1         = (const float*)d_in[3];
  const float* qw         = (const float*)d_in[4];
  const float* qb         = (const float*)d_in[5];
  const float* kvw        = (const float*)d_in[6];
  const float* kvb        = (const float*)d_in[7];
  const float* pw         = (const float*)d_in[8];
  const float* pb         = (const float*)d_in[9];
  const float* bias_table = (const float*)d_in[10];
  const float* g2         = (const float*)d_in[11];
  const float* b2         = (const float*)d_in[12];
  const float* w1         = (const float*)d_in[13];
  const float* bi1        = (const float*)d_in[14];
  const float* w2         = (const float*)d_in[15];
  const float* bi2        = (const float*)d_in[16];
  float* out = (float*)d_out;
  char* ws = (char*)d_ws;
  const long long MB = 1048576LL;
  unsigned short* wb    = (unsigned short*)(ws);
  unsigned short* q_in  = (unsigned short*)(ws + (long long)(1.5 * MB));
  unsigned short* kv_in = (unsigned short*)(ws + (long long)(65.5 * MB));
  unsigned short* qbuf  = (unsigned short*)(ws + (long long)(129.5 * MB));
  unsigned short* kbuf  = (unsigned short*)(ws + (long long)(193.5 * MB));
  unsigned short* vbuf  = (unsigned short*)(ws + (long long)(257.5 * MB));
  unsigned short* aoutb = kv_in;      // kv_in dead after qkv GEMM -> alias
  unsigned short* xn    = vbuf;       // vbuf dead after attn_k -> alias
  unsigned short* Hh    = q_in;       // dead after pgemm -> alias (134MB)

  prep_w<<<3072, 256, 0, stream>>>(qw, kvw, pw, w1, w2, wb);
  ln1_win<<<65536, 256, 0, stream>>>(x, g1, b1, q_in, kv_in);
  qkv_gemm<<<1024, 512, 0, stream>>>(q_in, kv_in, wb, qb, kvb, qbuf, kbuf, vbuf);
  attn_k<<<4096, 256, 0, stream>>>(qbuf, kbuf, vbuf, mask, bias_table, aoutb);
  pgemm<<<1024, 512, 0, stream>>>(aoutb, wb + 196608, pb, out, q_in, x);
  ln2_k<<<32768, 256, 0, stream>>>(out, g2, b2, xn);
  const unsigned short* w1b = wb + 262144;
  const unsigned short* w2b = wb + 524288;
  // M-sliced MLP: per half, GEMM1 over full hidden then one += pass on out.
  for (int h = 0; h < 2; h++){
    const long long R = (long long)h * 65536;
    mlp_gemm<4, 0, 0><<<dim3(8, 512), 256, 0, stream>>>(xn + R * 256, 256, w1b, 256,
                                                        bi1, Hh, 1024, nullptr);
    mlp_gemm<16, 1, 1><<<dim3(2, 512), 256, 0, stream>>>(Hh, 1024, w2b, 1024,
                                                         bi2, nullptr, 0, out + R * 256);
  }
}

// Round 19
// 731.831 us; speedup vs baseline: 1.0564x; 1.0564x over previous
//
#include <hip/hip_runtime.h>
#include <hip/hip_bf16.h>
#include <math.h>

#define SHIFT_ 4

typedef __attribute__((ext_vector_type(8))) short bh8;
typedef __attribute__((ext_vector_type(4))) short sh4;
typedef __attribute__((ext_vector_type(4))) float f4;
typedef __attribute__((ext_vector_type(8))) __bf16 bf8t;

static __device__ __forceinline__ f4 mfma16(bh8 a, bh8 b, f4 c){
  return __builtin_amdgcn_mfma_f32_16x16x32_bf16(
    __builtin_bit_cast(bf8t, a), __builtin_bit_cast(bf8t, b), c, 0, 0, 0);
}
static __device__ __forceinline__ unsigned short f2b(float f){
  unsigned u = __builtin_bit_cast(unsigned, f);
  u += 0x7fffu + ((u >> 16) & 1u);
  return (unsigned short)(u >> 16);
}
static __device__ __forceinline__ float b2f(unsigned short h){
  return __builtin_bit_cast(float, ((unsigned)h) << 16);
}
static __device__ __forceinline__ unsigned cvt_pk_bf16(float lo, float hi){
  unsigned r;
  asm("v_cvt_pk_bf16_f32 %0, %1, %2" : "=v"(r) : "v"(lo), "v"(hi));
  return r;
}
static __device__ __forceinline__ float gelu_f(float hv){
  float u = hv * (1.5957691216f + 0.0713548162f * hv * hv);
  return hv * __builtin_amdgcn_rcpf(1.f + __expf(-u));
}
static __device__ __forceinline__ void glds16(const unsigned short* g, unsigned short* l){
  __builtin_amdgcn_global_load_lds(
    (const __attribute__((address_space(1))) unsigned int*)g,
    (__attribute__((address_space(3))) unsigned int*)l, 16, 0, 0);
}

// ---------------- kernel 0: weights f32 -> bf16 (qw pre-scaled by d^-0.5) ---
__global__ __launch_bounds__(256) void prep_w(
    const float* __restrict__ qw, const float* __restrict__ kvw,
    const float* __restrict__ pw, const float* __restrict__ w1,
    const float* __restrict__ w2, unsigned short* __restrict__ wb){
  int i = blockIdx.x * 256 + threadIdx.x;   // 786432 total
  float v;
  if      (i < 65536)  v = qw[i] * 0.17677669529663687f;
  else if (i < 196608) v = kvw[i - 65536];
  else if (i < 262144) v = pw[i - 196608];
  else if (i < 524288) v = w1[i - 262144];
  else                 v = w2[i - 524288];
  wb[i] = f2b(v);
}

// ---------------- kernel 1: LN1 + roll(-4,-4) + window partition ------------
__global__ __launch_bounds__(256) void ln1_win(
    const float* __restrict__ x, const float* __restrict__ g1,
    const float* __restrict__ b1,
    unsigned short* __restrict__ q_in, unsigned short* __restrict__ kv_in){
  int rid  = blockIdx.x * 4 + (threadIdx.x >> 6);   // 0..262143
  int lane = threadIdx.x & 63;
  int d    = rid >> 17;
  int rem  = rid & 131071;          // w*64 + n
  int w = rem >> 6, n = rem & 63;
  int b = w >> 10, hb = (w >> 5) & 31, wbk = w & 31;
  int sh = (hb * 8 + (n >> 3) + SHIFT_) & 255;
  int sw = (wbk * 8 + (n & 7) + SHIFT_) & 255;
  const float* src = x + ((((size_t)(b * 2 + d)) * 256 + sh) * 256 + sw) * 256;
  float4 v = *(const float4*)(src + lane * 4);
  float s  = v.x + v.y + v.z + v.w;
  float ss = v.x * v.x + v.y * v.y + v.z * v.z + v.w * v.w;
  #pragma unroll
  for (int off = 1; off < 64; off <<= 1){ s += __shfl_xor(s, off); ss += __shfl_xor(ss, off); }
  float m    = s * (1.f / 256.f);
  float rstd = rsqrtf(ss * (1.f / 256.f) - m * m + 1e-5f);
  int c = lane * 4;
  float4 g  = *(const float4*)(g1 + c);
  float4 bb = *(const float4*)(b1 + c);
  sh4 o;
  o.x = (short)f2b((v.x - m) * rstd * g.x + bb.x);
  o.y = (short)f2b((v.y - m) * rstd * g.y + bb.y);
  o.z = (short)f2b((v.z - m) * rstd * g.z + bb.z);
  o.w = (short)f2b((v.w - m) * rstd * g.w + bb.w);
  unsigned short* dst = (d == 0 ? q_in : kv_in) + (size_t)rem * 256 + c;
  *(sh4*)dst = o;
}

// ---------------- fused QKV GEMM: 512 thr, block 128 rows x 3x256 cols ------
// LDS-staged epilogue: packed bf16 tile staged in sO (aliasing sA/sB), then
// cooperatively stored as 16B chunks -> full 64B-line writes.
__global__ __launch_bounds__(512, 4) void qkv_gemm(
    const unsigned short* __restrict__ q_in, const unsigned short* __restrict__ kv_in,
    const unsigned short* __restrict__ wpack,
    const float* __restrict__ qbias, const float* __restrict__ kvbias,
    unsigned short* __restrict__ qo, unsigned short* __restrict__ ko,
    unsigned short* __restrict__ vo){
  __shared__ unsigned short sMem[24576];   // 48KB: sA 128x64 | sB 256x64 ; sO aliases
  unsigned short (*sA)[64]  = (unsigned short(*)[64])sMem;
  unsigned short (*sB)[64]  = (unsigned short(*)[64])(sMem + 8192);
  unsigned short (*sO)[136] = (unsigned short(*)[136])sMem;   // 128x136 = 34.8KB
  int m0 = blockIdx.x * 128;
  int tid = threadIdx.x, lane = tid & 63, wid = tid >> 6;   // 8 waves
  int wm = wid >> 2, wn = wid & 3;
  int llo = lane & 15, lhi = lane >> 4;
  int lr = lane >> 3, lc = (lane & 7) * 8;
  const f4 FZ = {0.f, 0.f, 0.f, 0.f};
  for (int nt = 0; nt < 3; nt++){
    const unsigned short* A  = (nt == 0) ? q_in : kv_in;
    const unsigned short* Wt = wpack + nt * 65536;
    const float* bias = (nt == 0) ? qbias : kvbias + (nt - 1) * 256;
    unsigned short* outb = (nt == 0) ? qo : (nt == 1 ? ko : vo);
    float bscale = (nt == 0) ? 0.17677669529663687f : 1.f;
    f4 acc[4][4];
    for (int i = 0; i < 4; i++) for (int j = 0; j < 4; j++) acc[i][j] = FZ;
    for (int t = 0; t < 4; t++){
      int k0 = t * 64;
      #pragma unroll
      for (int c = 0; c < 2; c++){
        int rr = wid * 16 + c * 8;
        glds16(A + (size_t)(m0 + rr + lr) * 256 + k0 + lc, &sA[rr][0]);
      }
      #pragma unroll
      for (int c = 0; c < 4; c++){
        int rb = wid * 32 + c * 8;
        glds16(Wt + (size_t)(rb + lr) * 256 + k0 + lc, &sB[rb][0]);
      }
      __syncthreads();
      #pragma unroll
      for (int ks = 0; ks < 2; ks++){
        bh8 a[4], b[4];
        #pragma unroll
        for (int mi = 0; mi < 4; mi++) a[mi] = *(const bh8*)&sA[wm * 64 + mi * 16 + llo][ks * 32 + lhi * 8];
        #pragma unroll
        for (int nj = 0; nj < 4; nj++) b[nj] = *(const bh8*)&sB[wn * 64 + nj * 16 + llo][ks * 32 + lhi * 8];
        #pragma unroll
        for (int mi = 0; mi < 4; mi++)
          #pragma unroll
          for (int nj = 0; nj < 4; nj++)
            acc[mi][nj] = mfma16(b[nj], a[mi], acc[mi][nj]);   // swapped
      }
      __syncthreads();
    }
    // LDS-staged epilogue, two 128-col halves
    #pragma unroll
    for (int half = 0; half < 2; half++){
      if ((wn >> 1) == half){
        int cbase = (wn & 1) * 64;
        #pragma unroll
        for (int nj = 0; nj < 4; nj++){
          int cb = cbase + nj * 16 + lhi * 4;
          float4 bv = *(const float4*)(bias + half * 128 + cb);
          #pragma unroll
          for (int mi = 0; mi < 4; mi++){
            int rl = wm * 64 + mi * 16 + llo;
            uint2 p;
            p.x = cvt_pk_bf16(acc[mi][nj][0] + bv.x * bscale, acc[mi][nj][1] + bv.y * bscale);
            p.y = cvt_pk_bf16(acc[mi][nj][2] + bv.z * bscale, acc[mi][nj][3] + bv.w * bscale);
            *(uint2*)&sO[rl][cb] = p;
          }
        }
      }
      __syncthreads();
      #pragma unroll
      for (int it = 0; it < 4; it++){
        int idx = tid + it * 512;            // 0..2047 = 128 rows x 16 chunks
        int rl = idx >> 4, ch = (idx & 15) * 8;
        bh8 vv = *(const bh8*)&sO[rl][ch];
        *(bh8*)(outb + (size_t)(m0 + rl) * 256 + half * 128 + ch) = vv;
      }
      __syncthreads();   // sO reads done before next write/restage
    }
  }
}

// ---------------- kernel 3: attention, block = (window, 4-head group) -------
__global__ __launch_bounds__(256, 2) void attn_k(
    const unsigned short* __restrict__ q, const unsigned short* __restrict__ k,
    const unsigned short* __restrict__ v, const float* __restrict__ mask,
    const float* __restrict__ bias_table, unsigned short* __restrict__ aout){
  __shared__ unsigned short sMask[64][72];   // bf16 mask
  __shared__ unsigned short sVT[128][72];    // V^T (d-local x n) for this group
  __shared__ unsigned short sP[4][64][72];
  __shared__ float sBias[4][225];
  int bid = blockIdx.x;                      // 4096 = 2048 windows x 2 groups
  int w = bid >> 1, hg = bid & 1;
  int tid = threadIdx.x, lane = tid & 63, wid = tid >> 6;
  int hd = hg * 4 + wid;
  int llo = lane & 15, lhi = lane >> 4;
  const unsigned short* qp = q + (size_t)w * 64 * 256 + hd * 32;
  const unsigned short* kp = k + (size_t)w * 64 * 256 + hd * 32;
  bh8 af[4], bf[4];
  #pragma unroll
  for (int mi = 0; mi < 4; mi++) af[mi] = *(const bh8*)(qp + (size_t)(mi * 16 + llo) * 256 + lhi * 8);
  #pragma unroll
  for (int nj = 0; nj < 4; nj++) bf[nj] = *(const bh8*)(kp + (size_t)(nj * 16 + llo) * 256 + lhi * 8);
  const float* mrow = mask + (size_t)(w & 1023) * 4096;
  #pragma unroll
  for (int i = 0; i < 2; i++){
    int base = (tid + i * 256) * 8;          // 0..4088
    float4 u0 = *(const float4*)(mrow + base);
    float4 u1 = *(const float4*)(mrow + base + 4);
    int rr = base >> 6, cc = base & 63;
    uint4 p;
    p.x = cvt_pk_bf16(u0.x, u0.y); p.y = cvt_pk_bf16(u0.z, u0.w);
    p.z = cvt_pk_bf16(u1.x, u1.y); p.w = cvt_pk_bf16(u1.z, u1.w);
    *(uint4*)&sMask[rr][cc] = p;
  }
  {
    const unsigned short* vp = v + (size_t)w * 64 * 256 + hg * 128;
    #pragma unroll
    for (int it = 0; it < 4; it++){
      int idx = tid + it * 256;              // 0..1023
      int n = idx >> 4, dc = (idx & 15) * 8;
      bh8 vv = *(const bh8*)(vp + (size_t)n * 256 + dc);
      #pragma unroll
      for (int j = 0; j < 8; j++) sVT[dc + j][n] = (unsigned short)vv[j];
    }
  }
  for (int i = lane; i < 225; i += 64) sBias[wid][i] = bias_table[i * 8 + hd];
  const f4 FZ = {0.f, 0.f, 0.f, 0.f};
  f4 acc[4][4];
  #pragma unroll
  for (int mi = 0; mi < 4; mi++)
    #pragma unroll
    for (int nj = 0; nj < 4; nj++)
      acc[mi][nj] = mfma16(af[mi], bf[nj], FZ);
  __syncthreads();   // sMask + sVT ready
  #pragma unroll
  for (int mi = 0; mi < 4; mi++){
    #pragma unroll
    for (int r = 0; r < 4; r++){
      int rr = mi * 16 + lhi * 4 + r;
      int yi = rr >> 3, xi = rr & 7;
      float sv[4]; float mx = -1e30f;
      #pragma unroll
      for (int nj = 0; nj < 4; nj++){
        int cc = nj * 16 + llo;
        int idx = (yi - (cc >> 3) + 7) * 15 + (xi - (cc & 7) + 7);
        sv[nj] = acc[mi][nj][r] + sBias[wid][idx] + b2f(sMask[rr][cc]);
        mx = fmaxf(mx, sv[nj]);
      }
      #pragma unroll
      for (int off = 1; off < 16; off <<= 1) mx = fmaxf(mx, __shfl_xor(mx, off));
      float sum = 0.f;
      #pragma unroll
      for (int nj = 0; nj < 4; nj++){ sv[nj] = __expf(sv[nj] - mx); sum += sv[nj]; }
      #pragma unroll
      for (int off = 1; off < 16; off <<= 1) sum += __shfl_xor(sum, off);
      float inv = __builtin_amdgcn_rcpf(sum);
      #pragma unroll
      for (int nj = 0; nj < 4; nj++) sP[wid][rr][nj * 16 + llo] = f2b(sv[nj] * inv);
    }
  }
  f4 o[4][2];
  for (int mi = 0; mi < 4; mi++) for (int dj = 0; dj < 2; dj++) o[mi][dj] = FZ;
  #pragma unroll
  for (int ks = 0; ks < 2; ks++){
    bh8 pa[4], vb[2];
    #pragma unroll
    for (int mi = 0; mi < 4; mi++) pa[mi] = *(const bh8*)&sP[wid][mi * 16 + llo][ks * 32 + lhi * 8];
    #pragma unroll
    for (int dj = 0; dj < 2; dj++) vb[dj] = *(const bh8*)&sVT[wid * 32 + dj * 16 + llo][ks * 32 + lhi * 8];
    #pragma unroll
    for (int mi = 0; mi < 4; mi++)
      #pragma unroll
      for (int dj = 0; dj < 2; dj++)
        o[mi][dj] = mfma16(pa[mi], vb[dj], o[mi][dj]);
  }
  #pragma unroll
  for (int mi = 0; mi < 4; mi++)
    for (int dj = 0; dj < 2; dj++)
      for (int r = 0; r < 4; r++){
        int rr = mi * 16 + lhi * 4 + r, dd = dj * 16 + llo;
        aout[((size_t)w * 64 + rr) * 256 + hd * 32 + dd] = f2b(o[mi][dj][r]);
      }
}

// ---------------- P-projection GEMM, swapped orientation, vector epilogue ---
__global__ __launch_bounds__(512, 4) void pgemm(
    const unsigned short* __restrict__ A, const unsigned short* __restrict__ Wt,
    const float* __restrict__ bias,
    float* __restrict__ outf, const unsigned short* __restrict__ qin,
    const float* __restrict__ xsrc){
  __shared__ unsigned short sA[128][64];
  __shared__ unsigned short sB[256][64];
  int m0 = blockIdx.x * 128;
  int tid = threadIdx.x, lane = tid & 63, wid = tid >> 6;   // 8 waves
  int wm = wid >> 2, wn = wid & 3;
  int llo = lane & 15, lhi = lane >> 4;
  int lr = lane >> 3, lc = (lane & 7) * 8;
  const f4 FZ = {0.f, 0.f, 0.f, 0.f};
  f4 acc[4][4];
  for (int i = 0; i < 4; i++) for (int j = 0; j < 4; j++) acc[i][j] = FZ;
  for (int t = 0; t < 4; t++){
    int k0 = t * 64;
    #pragma unroll
    for (int c = 0; c < 2; c++){
      int rr = wid * 16 + c * 8;
      glds16(A + (size_t)(m0 + rr + lr) * 256 + k0 + lc, &sA[rr][0]);
    }
    #pragma unroll
    for (int c = 0; c < 4; c++){
      int rb = wid * 32 + c * 8;
      glds16(Wt + (size_t)(rb + lr) * 256 + k0 + lc, &sB[rb][0]);
    }
    __syncthreads();
    #pragma unroll
    for (int ks = 0; ks < 2; ks++){
      bh8 a[4], b[4];
      #pragma unroll
      for (int mi = 0; mi < 4; mi++) a[mi] = *(const bh8*)&sA[wm * 64 + mi * 16 + llo][ks * 32 + lhi * 8];
      #pragma unroll
      for (int nj = 0; nj < 4; nj++) b[nj] = *(const bh8*)&sB[wn * 64 + nj * 16 + llo][ks * 32 + lhi * 8];
      #pragma unroll
      for (int mi = 0; mi < 4; mi++)
        #pragma unroll
        for (int nj = 0; nj < 4; nj++)
          acc[mi][nj] = mfma16(b[nj], a[mi], acc[mi][nj]);   // swapped
    }
    __syncthreads();
  }
  #pragma unroll
  for (int mi = 0; mi < 4; mi++){
    int row = m0 + wm * 64 + mi * 16 + llo;
    int w = row >> 6, n = row & 63;
    int b = w >> 10, hb = (w >> 5) & 31, wbk = w & 31;
    int hh = (hb * 8 + (n >> 3) + SHIFT_) & 255;
    int ww = (wbk * 8 + (n & 7) + SHIFT_) & 255;
    size_t rbase = (((size_t)b * 256 + hh) * 256 + ww) * 256;
    size_t xbase = (((size_t)(b * 2) * 256 + hh) * 256 + ww) * 256;
    const unsigned short* qrow = qin + (size_t)row * 256;
    #pragma unroll
    for (int nj = 0; nj < 4; nj++){
      int cb = wn * 64 + nj * 16 + lhi * 4;
      float4 bv = *(const float4*)(bias + cb);
      uint2 qv = *(const uint2*)(qrow + cb);
      float4 xv = *(const float4*)(xsrc + xbase + cb);
      float4 o;
      o.x = acc[mi][nj][0] + bv.x + b2f((unsigned short)(qv.x & 0xffff)) + xv.x;
      o.y = acc[mi][nj][1] + bv.y + b2f((unsigned short)(qv.x >> 16))    + xv.y;
      o.z = acc[mi][nj][2] + bv.z + b2f((unsigned short)(qv.y & 0xffff)) + xv.z;
      o.w = acc[mi][nj][3] + bv.w + b2f((unsigned short)(qv.y >> 16))    + xv.w;
      *(float4*)(outf + rbase + cb) = o;
    }
  }
}

// ---------------- kernel 4: LN2 -> bf16 xn (row-major) ----------------------
__global__ __launch_bounds__(256) void ln2_k(
    const float* __restrict__ x1, const float* __restrict__ g2,
    const float* __restrict__ b2, unsigned short* __restrict__ xn){
  int rid  = blockIdx.x * 4 + (threadIdx.x >> 6);   // 0..131071
  int lane = threadIdx.x & 63;
  const float* xr = x1 + (size_t)rid * 256;
  float4 v = *(const float4*)(xr + lane * 4);
  float s  = v.x + v.y + v.z + v.w;
  float ss = v.x * v.x + v.y * v.y + v.z * v.z + v.w * v.w;
  #pragma unroll
  for (int off = 1; off < 64; off <<= 1){ s += __shfl_xor(s, off); ss += __shfl_xor(ss, off); }
  float m    = s * (1.f / 256.f);
  float rstd = rsqrtf(ss * (1.f / 256.f) - m * m + 1e-5f);
  int c = lane * 4;
  float4 g  = *(const float4*)(g2 + c);
  float4 bb = *(const float4*)(b2 + c);
  sh4 o;
  o.x = (short)f2b((v.x - m) * rstd * g.x + bb.x);
  o.y = (short)f2b((v.y - m) * rstd * g.y + bb.y);
  o.z = (short)f2b((v.z - m) * rstd * g.z + bb.z);
  o.w = (short)f2b((v.w - m) * rstd * g.w + bb.w);
  *(sh4*)(xn + (size_t)rid * 256 + c) = o;
}

// ---------------- kernel 5: m97-template GEMM for the MLP -------------------
// EPI 0: gelu -> bf16 H via LDS-staged full-line stores. EPI 1: f32 += out.
template<int KSTEPS, int EPI, int BIASF>
__global__ __launch_bounds__(256, 3) void mlp_gemm(
    const unsigned short* __restrict__ A, int lda,
    const unsigned short* __restrict__ Bw, int ldb,
    const float* __restrict__ bias,
    unsigned short* __restrict__ outb, int ldo,
    float* __restrict__ outf){
  __shared__ unsigned short sMem[17408];   // 34.8KB: sA|sB (32KB); sO aliases
  unsigned short (*sA)[64]  = (unsigned short(*)[64])sMem;
  unsigned short (*sB)[64]  = (unsigned short(*)[64])(sMem + 8192);
  unsigned short (*sO)[136] = (unsigned short(*)[136])sMem;   // 128x136
  int n0 = blockIdx.x * 128, m0 = blockIdx.y * 128;
  int tid = threadIdx.x, lane = tid & 63, wid = tid >> 6;
  int wm = wid >> 1, wn = wid & 1;
  int llo = lane & 15, lhi = lane >> 4;
  int lr = lane >> 3, lc = (lane & 7) * 8;
  const f4 FZ = {0.f, 0.f, 0.f, 0.f};
  f4 acc[4][4];
  for (int i = 0; i < 4; i++) for (int j = 0; j < 4; j++) acc[i][j] = FZ;

  for (int t = 0; t < KSTEPS; t++){
    int k0 = t * 64;
    #pragma unroll
    for (int c = 0; c < 4; c++){
      int rr = wid * 32 + c * 8 + lr;
      glds16(A  + (size_t)(m0 + rr) * lda + k0 + lc, &sA[wid * 32 + c * 8][0]);
      glds16(Bw + (size_t)(n0 + rr) * ldb + k0 + lc, &sB[wid * 32 + c * 8][0]);
    }
    __syncthreads();
    #pragma unroll
    for (int ks = 0; ks < 2; ks++){
      bh8 a[4], b[4];
      #pragma unroll
      for (int mi = 0; mi < 4; mi++) a[mi] = *(const bh8*)&sA[wm * 64 + mi * 16 + llo][ks * 32 + lhi * 8];
      #pragma unroll
      for (int nj = 0; nj < 4; nj++) b[nj] = *(const bh8*)&sB[wn * 64 + nj * 16 + llo][ks * 32 + lhi * 8];
      #pragma unroll
      for (int mi = 0; mi < 4; mi++)
        #pragma unroll
        for (int nj = 0; nj < 4; nj++){
          if (EPI == 0) acc[mi][nj] = mfma16(b[nj], a[mi], acc[mi][nj]);   // swapped
          else          acc[mi][nj] = mfma16(a[mi], b[nj], acc[mi][nj]);
        }
    }
    __syncthreads();
  }
  if (EPI == 0){
    #pragma unroll
    for (int nj = 0; nj < 4; nj++){
      int cb = wn * 64 + nj * 16 + lhi * 4;    // 0..127
      float4 bv = *(const float4*)(bias + n0 + cb);
      #pragma unroll
      for (int mi = 0; mi < 4; mi++){
        int rl = wm * 64 + mi * 16 + llo;
        uint2 p;
        p.x = cvt_pk_bf16(gelu_f(acc[mi][nj][0] + bv.x), gelu_f(acc[mi][nj][1] + bv.y));
        p.y = cvt_pk_bf16(gelu_f(acc[mi][nj][2] + bv.z), gelu_f(acc[mi][nj][3] + bv.w));
        *(uint2*)&sO[rl][cb] = p;
      }
    }
    __syncthreads();
    #pragma unroll
    for (int it = 0; it < 8; it++){
      int idx = tid + it * 256;                // 0..2047 = 128 rows x 16 chunks
      int rl = idx >> 4, ch = (idx & 15) * 8;
      bh8 vv = *(const bh8*)&sO[rl][ch];
      *(bh8*)(outb + (size_t)(m0 + rl) * ldo + n0 + ch) = vv;
    }
  } else {
    #pragma unroll
    for (int mi = 0; mi < 4; mi++)
      #pragma unroll
      for (int nj = 0; nj < 4; nj++){
        int col = n0 + wn * 64 + nj * 16 + llo;
        float bv = BIASF ? bias[col] : 0.f;
        #pragma unroll
        for (int r = 0; r < 4; r++){
          int row = m0 + wm * 64 + mi * 16 + lhi * 4 + r;
          outf[(size_t)row * 256 + col] += acc[mi][nj][r] + bv;
        }
      }
  }
}

extern "C" void kernel_launch(void* const* d_in, const int* in_sizes, int n_in,
                              void* d_out, int out_size, void* d_ws, size_t ws_size,
                              hipStream_t stream){
  const float* x          = (const float*)d_in[0];
  const float* mask       = (const float*)d_in[1];
  const float* g1         = (const float*)d_in[2];
  const float* b1         = (const float*)d_in[3];
  const float* qw         = (const float*)d_in[4];
  const float* qb         = (const float*)d_in[5];
  const float* kvw        = (const float*)d_in[6];
  const float* kvb        = (const float*)d_in[7];
  const float* pw         = (const float*)d_in[8];
  const float* pb         = (const float*)d_in[9];
  const float* bias_table = (const float*)d_in[10];
  const float* g2         = (const float*)d_in[11];
  const float* b2         = (const float*)d_in[12];
  const float* w1         = (const float*)d_in[13];
  const float* bi1        = (const float*)d_in[14];
  const float* w2         = (const float*)d_in[15];
  const float* bi2        = (const float*)d_in[16];
  float* out = (float*)d_out;
  char* ws = (char*)d_ws;
  const long long MB = 1048576LL;
  unsigned short* wb    = (unsigned short*)(ws);
  unsigned short* q_in  = (unsigned short*)(ws + (long long)(1.5 * MB));
  unsigned short* kv_in = (unsigned short*)(ws + (long long)(65.5 * MB));
  unsigned short* qbuf  = (unsigned short*)(ws + (long long)(129.5 * MB));
  unsigned short* kbuf  = (unsigned short*)(ws + (long long)(193.5 * MB));
  unsigned short* vbuf  = (unsigned short*)(ws + (long long)(257.5 * MB));
  unsigned short* aoutb = kv_in;      // kv_in dead after qkv GEMM -> alias
  unsigned short* xn    = vbuf;       // vbuf dead after attn_k -> alias
  unsigned short* Hh    = q_in;       // dead after pgemm -> alias (134MB)

  prep_w<<<3072, 256, 0, stream>>>(qw, kvw, pw, w1, w2, wb);
  ln1_win<<<65536, 256, 0, stream>>>(x, g1, b1, q_in, kv_in);
  qkv_gemm<<<1024, 512, 0, stream>>>(q_in, kv_in, wb, qb, kvb, qbuf, kbuf, vbuf);
  attn_k<<<4096, 256, 0, stream>>>(qbuf, kbuf, vbuf, mask, bias_table, aoutb);
  pgemm<<<1024, 512, 0, stream>>>(aoutb, wb + 196608, pb, out, q_in, x);
  ln2_k<<<32768, 256, 0, stream>>>(out, g2, b2, xn);
  const unsigned short* w1b = wb + 262144;
  const unsigned short* w2b = wb + 524288;
  // M-sliced MLP: per half, GEMM1 over full hidden then one += pass on out.
  for (int h = 0; h < 2; h++){
    const long long R = (long long)h * 65536;
    mlp_gemm<4, 0, 0><<<dim3(8, 512), 256, 0, stream>>>(xn + R * 256, 256, w1b, 256,
                                                        bi1, Hh, 1024, nullptr);
    mlp_gemm<16, 1, 1><<<dim3(2, 512), 256, 0, stream>>>(Hh, 1024, w2b, 1024,
                                                         bi2, nullptr, 0, out + R * 256);
  }
}